// Round 3
// baseline (3119.014 us; speedup 1.0000x reference)
//
#include <hip/hip_runtime.h>

typedef unsigned short u16;
typedef unsigned int   u32;

typedef __attribute__((ext_vector_type(8))) __bf16 bf16x8;
typedef __attribute__((ext_vector_type(8))) unsigned short u16x8;
typedef __attribute__((ext_vector_type(4))) float  f32x4;

#define C      256
#define KCAT   768
#define OUTC   128
#define LN_EPS 1e-5f

__device__ __forceinline__ float bf2f(u16 u) {
    u32 i = ((u32)u) << 16; float f; __builtin_memcpy(&f, &i, 4); return f;
}
__device__ __forceinline__ u16 f2bf(float f) {
    u32 i; __builtin_memcpy(&i, &f, 4);
    u32 r = (i + 0x7FFFu + ((i >> 16) & 1u)) >> 16;
    return (u16)r;
}
__device__ __forceinline__ void load_lds16(const void* g, void* l) {
    __builtin_amdgcn_global_load_lds((const __attribute__((address_space(1))) u32*)g,
                                     (__attribute__((address_space(3))) u32*)l, 16, 0, 0);
}

// ---- weight prep (fp32 in): Wcat[L][n][768] bf16 gate-scaled, bcat[L][n] fp32,
//      Woutb[128][256] bf16 -------------------------------------------------------
__global__ void prep_weights(const float* wlA, const float* w0A, const float* w1A,
                             const float* blA, const float* b0A, const float* b1A,
                             const float* gateA,
                             const float* wlB, const float* w0B, const float* w1B,
                             const float* blB, const float* b0B, const float* b1B,
                             const float* gateB,
                             const float* Wout,
                             u16* __restrict__ Wcat, float* __restrict__ bcat,
                             u16* __restrict__ Woutb)
{
    int idx = blockIdx.x * 256 + threadIdx.x;
    if (idx < 2 * C * KCAT) {
        int L   = idx / (C * KCAT);
        int rem = idx - L * (C * KCAT);
        int n   = rem / KCAT;
        int k   = rem - n * KCAT;
        const float* wl = L ? wlB : wlA;
        const float* w0 = L ? w0B : w0A;
        const float* w1 = L ? w1B : w1A;
        float g = 1.f / (1.f + expf(-((L ? gateB : gateA)[0])));
        float v;
        if (k < 256)      v = wl[n * 256 + k];
        else if (k < 512) v = (1.f - g) * w0[n * 256 + (k - 256)];
        else              v = g * w1[n * 256 + (k - 512)];
        Wcat[idx] = f2bf(v);
        if (idx < 2 * C) {
            int LL = idx / C, nn = idx & 255;
            float gg = 1.f / (1.f + expf(-((LL ? gateB : gateA)[0])));
            bcat[idx] = (LL ? blB : blA)[nn]
                      + (1.f - gg) * (LL ? b0B : b0A)[nn]
                      + gg * (LL ? b1B : b1A)[nn];
        }
    } else {
        int j = idx - 2 * C * KCAT;          // < OUTC*C = 32768
        if (j < OUTC * C) Woutb[j] = f2bf(Wout[j]);
    }
}

// ---- scatter: one wave per edge; agg[src] += h[dst] (fp32 atomics); deg[dst] += 1 --
template <bool H_BF16>
__global__ void scatter_kernel(const int* __restrict__ ei, const void* __restrict__ hv_,
                               float* __restrict__ agg, float* __restrict__ deg,
                               int E, int Nn)
{
    int e = blockIdx.x * 4 + (threadIdx.x >> 6);
    if (e >= E) return;
    int lane = threadIdx.x & 63;
    int src = ei[e];
    int dst = ei[E + e];
    if ((unsigned)src >= (unsigned)Nn || (unsigned)dst >= (unsigned)Nn) return;
    float v0, v1, v2, v3;
    if (H_BF16) {
        const u16* hp = (const u16*)hv_ + (size_t)dst * C + lane * 4;
        ushort4 hv = *(const ushort4*)hp;
        v0 = bf2f(hv.x); v1 = bf2f(hv.y); v2 = bf2f(hv.z); v3 = bf2f(hv.w);
    } else {
        const float* hp = (const float*)hv_ + (size_t)dst * C + lane * 4;
        float4 hv = *(const float4*)hp;
        v0 = hv.x; v1 = hv.y; v2 = hv.z; v3 = hv.w;
    }
    float* ap = agg + (size_t)src * C + lane * 4;
    unsafeAtomicAdd(ap + 0, v0);
    unsafeAtomicAdd(ap + 1, v1);
    unsafeAtomicAdd(ap + 2, v2);
    unsafeAtomicAdd(ap + 3, v3);
    if (lane == 0) unsafeAtomicAdd(deg + dst, 1.0f);
}

// ---- fused layer GEMM: [agg/deg | h | x0](64x768) @ Wcat^T -> relu -> LN -> bf16 ---
// block: 256 thr (4 waves, 2x2), tile M=64 x N=256 (full row in block), BK=32.
// fp32 A segments are normalized/converted to bf16 in registers during staging;
// bf16 h uses the global_load_lds fast path.
template <bool H_BF16>
__global__ __launch_bounds__(256) void layer_gemm(
    const float* __restrict__ Aagg, const float* __restrict__ deg,
    const void* __restrict__ Ah_, const float* __restrict__ Ax,
    const u16* __restrict__ W,    // [256][768] bf16
    const float* __restrict__ bcat,
    const float* __restrict__ lns, const float* __restrict__ lnb,
    u16* __restrict__ Hout, int Nnodes)
{
    __shared__ u16 Alds[64 * 32];    // [row][k], 4 KB
    __shared__ u16 Blds[256 * 32];   // [n][k], 16 KB
    __shared__ float lnpart[64][2][2];

    const int tid = threadIdx.x;
    const int wave = tid >> 6, lane = tid & 63;
    const int wave_m = wave & 1, wave_n = wave >> 1;
    const int q = lane >> 4, l15 = lane & 15;
    const int m0 = blockIdx.x * 64;

    // A staging: chunk == wave, lane covers (row = wave*16 + lane/4, k = (lane%4)*8)
    int a_row  = wave * 16 + (lane >> 2);
    int a_node = m0 + a_row; if (a_node >= Nnodes) a_node = Nnodes - 1;
    const int kk8 = (lane & 3) * 8;
    const size_t a_off = (size_t)a_node * C + kk8;
    u16* AldsW = Alds + wave * 512;
    const float invd = 1.0f / fmaxf(deg[a_node], 1.0f);

    // B staging: 16 chunks, wave does cb = wave*4 + i
    const u16* bg[4]; u16* bl[4];
    #pragma unroll
    for (int i = 0; i < 4; ++i) {
        int cb = wave * 4 + i;
        int n_row = cb * 16 + (lane >> 2);
        bg[i] = W + n_row * KCAT + kk8;
        bl[i] = Blds + cb * 512;
    }

    f32x4 acc[2][8] = {};

    for (int kt = 0; kt < 24; ++kt) {
        int k0 = kt * 32;
        bool reg_path = true;
        const float* fsrc = nullptr;
        float scale = 1.0f;
        if (kt < 8)       { fsrc = Aagg + a_off + k0; scale = invd; }
        else if (kt < 16) {
            if (H_BF16) { reg_path = false; load_lds16((const u16*)Ah_ + a_off + (k0 & 255), AldsW); }
            else          fsrc = (const float*)Ah_ + a_off + (k0 & 255);
        }
        else              { fsrc = Ax + a_off + (k0 & 255); }
        if (reg_path) {
            float4 v0 = *(const float4*)(fsrc);
            float4 v1 = *(const float4*)(fsrc + 4);
            u16x8 o;
            o[0] = f2bf(v0.x * scale); o[1] = f2bf(v0.y * scale);
            o[2] = f2bf(v0.z * scale); o[3] = f2bf(v0.w * scale);
            o[4] = f2bf(v1.x * scale); o[5] = f2bf(v1.y * scale);
            o[6] = f2bf(v1.z * scale); o[7] = f2bf(v1.w * scale);
            *(u16x8*)(AldsW + lane * 8) = o;    // lane*16B: same layout as load_lds16
        }
        #pragma unroll
        for (int i = 0; i < 4; ++i) load_lds16(bg[i] + k0, bl[i]);
        __syncthreads();

        bf16x8 af[2], bfr[8];
        #pragma unroll
        for (int t = 0; t < 2; ++t)
            af[t] = *(const bf16x8*)&Alds[(wave_m * 32 + t * 16 + l15) * 32 + q * 8];
        #pragma unroll
        for (int f = 0; f < 8; ++f)
            bfr[f] = *(const bf16x8*)&Blds[(wave_n * 128 + f * 16 + l15) * 32 + q * 8];
        #pragma unroll
        for (int t = 0; t < 2; ++t)
            #pragma unroll
            for (int f = 0; f < 8; ++f)
                acc[t][f] = __builtin_amdgcn_mfma_f32_16x16x32_bf16(af[t], bfr[f], acc[t][f], 0, 0, 0);
        __syncthreads();
    }

    // epilogue: +bias, relu, LayerNorm over the 256 cols of each row, write bf16
    float bias[8], lsc[8], lbi[8];
    #pragma unroll
    for (int f = 0; f < 8; ++f) {
        int n = wave_n * 128 + f * 16 + l15;
        bias[f] = bcat[n]; lsc[f] = lns[n]; lbi[f] = lnb[n];
    }
    float s1[2][4], s2[2][4];
    #pragma unroll
    for (int t = 0; t < 2; ++t)
        #pragma unroll
        for (int r = 0; r < 4; ++r) {
            float p = 0.f, pp = 0.f;
            #pragma unroll
            for (int f = 0; f < 8; ++f) {
                float v = acc[t][f][r] + bias[f];
                v = fmaxf(v, 0.f);
                acc[t][f][r] = v;
                p += v; pp += v * v;
            }
            #pragma unroll
            for (int off = 1; off < 16; off <<= 1) {
                p  += __shfl_xor(p,  off, 16);
                pp += __shfl_xor(pp, off, 16);
            }
            s1[t][r] = p; s2[t][r] = pp;
        }
    if (l15 == 0) {
        #pragma unroll
        for (int t = 0; t < 2; ++t)
            #pragma unroll
            for (int r = 0; r < 4; ++r) {
                int row = wave_m * 32 + t * 16 + q * 4 + r;
                lnpart[row][wave_n][0] = s1[t][r];
                lnpart[row][wave_n][1] = s2[t][r];
            }
    }
    __syncthreads();
    #pragma unroll
    for (int t = 0; t < 2; ++t)
        #pragma unroll
        for (int r = 0; r < 4; ++r) {
            int row = wave_m * 32 + t * 16 + q * 4 + r;
            int node = m0 + row;
            if (node < Nnodes) {
                float S1 = lnpart[row][0][0] + lnpart[row][1][0];
                float S2 = lnpart[row][0][1] + lnpart[row][1][1];
                float mean = S1 * (1.f / 256.f);
                float var  = S2 * (1.f / 256.f) - mean * mean;
                var = fmaxf(var, 0.f);
                float rstd = rsqrtf(var + LN_EPS);
                u16* op = Hout + (size_t)node * C;
                #pragma unroll
                for (int f = 0; f < 8; ++f) {
                    int n = wave_n * 128 + f * 16 + l15;
                    op[n] = f2bf((acc[t][f][r] - mean) * rstd * lsc[f] + lbi[f]);
                }
            }
        }
}

// ---- final GEMM: h2(bf16, in d_out) @ Woutb^T(128x256) + bout -> fp32, in place ----
// Safe in place: each block reads only its own 64 rows (all global reads drain at the
// pre-epilogue barrier) and writes only those rows; rows are block-private.
__global__ __launch_bounds__(256) void final_gemm(
    const u16* __restrict__ A, const u16* __restrict__ W,
    const float* __restrict__ bout, float* __restrict__ out, int Nnodes)
{
    __shared__ u16 Alds[64 * 32];    // 4 KB
    __shared__ u16 Blds[128 * 32];   // 8 KB

    const int tid = threadIdx.x;
    const int wave = tid >> 6, lane = tid & 63;
    const int wave_m = wave & 1, wave_n = wave >> 1;
    const int q = lane >> 4, l15 = lane & 15;
    const int m0 = blockIdx.x * 64;

    int a_row  = wave * 16 + (lane >> 2);
    int a_node = m0 + a_row; if (a_node >= Nnodes) a_node = Nnodes - 1;
    const int kk8 = (lane & 3) * 8;
    const size_t a_off = (size_t)a_node * C + kk8;
    u16* AldsW = Alds + wave * 512;

    const u16* bg[2]; u16* bl[2];
    #pragma unroll
    for (int i = 0; i < 2; ++i) {
        int cb = wave * 2 + i;
        int n_row = cb * 16 + (lane >> 2);
        bg[i] = W + n_row * 256 + kk8;
        bl[i] = Blds + cb * 512;
    }

    f32x4 acc[2][4] = {};

    for (int kt = 0; kt < 8; ++kt) {
        int k0 = kt * 32;
        load_lds16(A + a_off + k0, AldsW);
        #pragma unroll
        for (int i = 0; i < 2; ++i) load_lds16(bg[i] + k0, bl[i]);
        __syncthreads();

        bf16x8 af[2], bfr[4];
        #pragma unroll
        for (int t = 0; t < 2; ++t)
            af[t] = *(const bf16x8*)&Alds[(wave_m * 32 + t * 16 + l15) * 32 + q * 8];
        #pragma unroll
        for (int f = 0; f < 4; ++f)
            bfr[f] = *(const bf16x8*)&Blds[(wave_n * 64 + f * 16 + l15) * 32 + q * 8];
        #pragma unroll
        for (int t = 0; t < 2; ++t)
            #pragma unroll
            for (int f = 0; f < 4; ++f)
                acc[t][f] = __builtin_amdgcn_mfma_f32_16x16x32_bf16(af[t], bfr[f], acc[t][f], 0, 0, 0);
        __syncthreads();
    }

    float bias[4];
    #pragma unroll
    for (int f = 0; f < 4; ++f) bias[f] = bout[wave_n * 64 + f * 16 + l15];
    #pragma unroll
    for (int t = 0; t < 2; ++t)
        #pragma unroll
        for (int r = 0; r < 4; ++r) {
            int row = wave_m * 32 + t * 16 + q * 4 + r;
            int node = m0 + row;
            if (node < Nnodes) {
                float* op = out + (size_t)node * OUTC;
                #pragma unroll
                for (int f = 0; f < 4; ++f) {
                    int n = wave_n * 64 + f * 16 + l15;
                    op[n] = acc[t][f][r] + bias[f];
                }
            }
        }
}

extern "C" void kernel_launch(void* const* d_in, const int* in_sizes, int n_in,
                              void* d_out, int out_size, void* d_ws, size_t ws_size,
                              hipStream_t stream)
{
    const float* x    = (const float*)d_in[0];
    const int*   ei0  = (const int*)d_in[1];
    const int*   ei1  = (const int*)d_in[2];
    const float* wl0  = (const float*)d_in[3];
    const float* bl0  = (const float*)d_in[4];
    const float* w00  = (const float*)d_in[5];
    const float* b00  = (const float*)d_in[6];
    const float* w10  = (const float*)d_in[7];
    const float* b10  = (const float*)d_in[8];
    const float* gate0= (const float*)d_in[9];
    const float* lns0 = (const float*)d_in[10];
    const float* lnb0 = (const float*)d_in[11];
    const float* wl1  = (const float*)d_in[12];
    const float* bl1  = (const float*)d_in[13];
    const float* w01  = (const float*)d_in[14];
    const float* b01  = (const float*)d_in[15];
    const float* w11  = (const float*)d_in[16];
    const float* b11  = (const float*)d_in[17];
    const float* gate1= (const float*)d_in[18];
    const float* lns1 = (const float*)d_in[19];
    const float* lnb1 = (const float*)d_in[20];
    const float* Wout = (const float*)d_in[21];
    const float* bout = (const float*)d_in[22];

    const int N = in_sizes[0] / C;     // 100000
    const int E = in_sizes[1] / 2;     // 400000

    // workspace (~155 MiB): [Wcat][Woutb][bcat][deg|agg][h1]
    char* w = (char*)d_ws;
    u16*   Wcat  = (u16*)w;   w += (size_t)2 * C * KCAT * 2;           // 786,432 B
    u16*   Woutb = (u16*)w;   w += (size_t)OUTC * C * 2;               // 65,536 B
    float* bcat  = (float*)w; w += 4096;
    float* deg   = (float*)w; w += ((size_t)N * 4 + 255) & ~255ull;
    float* agg   = (float*)w; w += (size_t)N * C * 4;                  // 102.4 MB
    u16*   h1    = (u16*)w;   w += (size_t)N * C * 2;                  // 51.2 MB

    const size_t degagg_bytes = (((size_t)N * 4 + 255) & ~255ull) + (size_t)N * C * 4;
    const int sc_grid = (E + 3) / 4;
    const int gm_grid = (N + 63) / 64;
    u16* h2 = (u16*)d_out;   // layer-B bf16 output lives in d_out, overwritten in place

    // weights (layer processed FIRST uses params-index-1)
    prep_weights<<<(2 * C * KCAT + OUTC * C) / 256, 256, 0, stream>>>(
        wl1, w01, w11, bl1, b01, b11, gate1,
        wl0, w00, w10, bl0, b00, b10, gate0,
        Wout, Wcat, bcat, Woutb);

    // ---- layer A: edge_index_r1, params *1, h = x (fp32) ----
    hipMemsetAsync(deg, 0, degagg_bytes, stream);
    scatter_kernel<false><<<sc_grid, 256, 0, stream>>>(ei1, x, agg, deg, E, N);
    layer_gemm<false><<<gm_grid, 256, 0, stream>>>(agg, deg, x, x, Wcat, bcat,
                                                   lns1, lnb1, h1, N);

    // ---- layer B: edge_index_r0, params *0, h = h1 (bf16) ----
    hipMemsetAsync(deg, 0, degagg_bytes, stream);
    scatter_kernel<true><<<sc_grid, 256, 0, stream>>>(ei0, h1, agg, deg, E, N);
    layer_gemm<true><<<gm_grid, 256, 0, stream>>>(agg, deg, h1, x, Wcat + C * KCAT,
                                                  bcat + C, lns0, lnb0, h2, N);

    // ---- output projection (in place over d_out) ----
    final_gemm<<<gm_grid, 256, 0, stream>>>(h2, Woutb, bout, (float*)d_out, N);
}

// Round 4
// 658.059 us; speedup vs baseline: 4.7397x; 4.7397x over previous
//
#include <hip/hip_runtime.h>

typedef unsigned short u16;
typedef unsigned int   u32;

typedef __attribute__((ext_vector_type(8))) __bf16 bf16x8;
typedef __attribute__((ext_vector_type(8))) unsigned short u16x8;
typedef __attribute__((ext_vector_type(4))) float  f32x4;

#define C      256
#define KCAT   768
#define OUTC   128
#define LN_EPS 1e-5f

__device__ __forceinline__ float bf2f(u16 u) {
    u32 i = ((u32)u) << 16; float f; __builtin_memcpy(&f, &i, 4); return f;
}
__device__ __forceinline__ u16 f2bf(float f) {
    u32 i; __builtin_memcpy(&i, &f, 4);
    u32 r = (i + 0x7FFFu + ((i >> 16) & 1u)) >> 16;
    return (u16)r;
}
__device__ __forceinline__ void load_lds16(const void* g, void* l) {
    __builtin_amdgcn_global_load_lds((const __attribute__((address_space(1))) u32*)g,
                                     (__attribute__((address_space(3))) u32*)l, 16, 0, 0);
}

// ---- weight prep (fp32 in): Wcat[L][n][768] bf16 gate-scaled, bcat[L][n] fp32,
//      Woutb[128][256] bf16 -------------------------------------------------------
__global__ void prep_weights(const float* wlA, const float* w0A, const float* w1A,
                             const float* blA, const float* b0A, const float* b1A,
                             const float* gateA,
                             const float* wlB, const float* w0B, const float* w1B,
                             const float* blB, const float* b0B, const float* b1B,
                             const float* gateB,
                             const float* Wout,
                             u16* __restrict__ Wcat, float* __restrict__ bcat,
                             u16* __restrict__ Woutb)
{
    int idx = blockIdx.x * 256 + threadIdx.x;
    if (idx < 2 * C * KCAT) {
        int L   = idx / (C * KCAT);
        int rem = idx - L * (C * KCAT);
        int n   = rem / KCAT;
        int k   = rem - n * KCAT;
        const float* wl = L ? wlB : wlA;
        const float* w0 = L ? w0B : w0A;
        const float* w1 = L ? w1B : w1A;
        float g = 1.f / (1.f + expf(-((L ? gateB : gateA)[0])));
        float v;
        if (k < 256)      v = wl[n * 256 + k];
        else if (k < 512) v = (1.f - g) * w0[n * 256 + (k - 256)];
        else              v = g * w1[n * 256 + (k - 512)];
        Wcat[idx] = f2bf(v);
        if (idx < 2 * C) {
            int LL = idx / C, nn = idx & 255;
            float gg = 1.f / (1.f + expf(-((LL ? gateB : gateA)[0])));
            bcat[idx] = (LL ? blB : blA)[nn]
                      + (1.f - gg) * (LL ? b0B : b0A)[nn]
                      + gg * (LL ? b1B : b1A)[nn];
        }
    } else {
        int j = idx - 2 * C * KCAT;          // < OUTC*C = 32768
        if (j < OUTC * C) Woutb[j] = f2bf(Wout[j]);
    }
}

// ================= CSR build ======================================================
__global__ void count_edges(const int* __restrict__ ei, int* __restrict__ counts,
                            int* __restrict__ degcnt, int E, int Nn)
{
    int idx = blockIdx.x * 256 + threadIdx.x;
    if (idx >= E) return;
    int s = ei[idx], d = ei[E + idx];
    if ((unsigned)s >= (unsigned)Nn || (unsigned)d >= (unsigned)Nn) return;
    atomicAdd(counts + s, 1);
    atomicAdd(degcnt + d, 1);
}

__global__ void block_sums(const int* __restrict__ counts, int* __restrict__ partials, int n)
{
    int i = blockIdx.x * 256 + threadIdx.x;
    int v = (i < n) ? counts[i] : 0;
    #pragma unroll
    for (int off = 32; off; off >>= 1) v += __shfl_down(v, off, 64);
    __shared__ int ws[4];
    if ((threadIdx.x & 63) == 0) ws[threadIdx.x >> 6] = v;
    __syncthreads();
    if (threadIdx.x == 0) partials[blockIdx.x] = ws[0] + ws[1] + ws[2] + ws[3];
}

// single block, 1024 thr: exclusive scan of nblk (<=1024) partials
__global__ void scan_partials(int* __restrict__ partials, int nblk)
{
    __shared__ int buf[1024];
    int tid = threadIdx.x;
    int v = (tid < nblk) ? partials[tid] : 0;
    buf[tid] = v; __syncthreads();
    for (int off = 1; off < 1024; off <<= 1) {
        int t = (tid >= off) ? buf[tid - off] : 0;
        __syncthreads();
        buf[tid] += t;
        __syncthreads();
    }
    if (tid < nblk) partials[tid] = buf[tid] - v;
}

// exclusive scan within block + partials[b]; overwrites counts with cursor(=offset)
__global__ void make_offsets(int* __restrict__ counts_cursor, const int* __restrict__ partials,
                             int* __restrict__ offsets, int n)
{
    __shared__ int buf[256];
    int i = blockIdx.x * 256 + threadIdx.x;
    int cnt = (i < n) ? counts_cursor[i] : 0;
    buf[threadIdx.x] = cnt; __syncthreads();
    for (int off = 1; off < 256; off <<= 1) {
        int t = (threadIdx.x >= off) ? buf[threadIdx.x - off] : 0;
        __syncthreads();
        buf[threadIdx.x] += t;
        __syncthreads();
    }
    int off = partials[blockIdx.x] + buf[threadIdx.x] - cnt;
    if (i < n) {
        offsets[i] = off;
        counts_cursor[i] = off;
        if (i == n - 1) offsets[n] = off + cnt;
    }
}

__global__ void fill_edges(const int* __restrict__ ei, int* __restrict__ cursor,
                           int* __restrict__ edgedst, int E, int Nn)
{
    int idx = blockIdx.x * 256 + threadIdx.x;
    if (idx >= E) return;
    int s = ei[idx], d = ei[E + idx];
    if ((unsigned)s >= (unsigned)Nn || (unsigned)d >= (unsigned)Nn) return;
    int p = atomicAdd(cursor + s, 1);
    edgedst[p] = d;
}

// ---- gather: one wave per node; agg[i] = (1/clip(deg[i],1)) * sum_{e in CSR[i]} h[dst[e]]
// writes bf16 directly (what the GEMM consumes)
template <bool H_BF16>
__global__ __launch_bounds__(256) void gather_kernel(
    const int* __restrict__ offsets, const int* __restrict__ edgedst,
    const int* __restrict__ degcnt, const void* __restrict__ h_,
    u16* __restrict__ aggb, int Nn)
{
    int node = blockIdx.x * 4 + (threadIdx.x >> 6);
    if (node >= Nn) return;
    int lane = threadIdx.x & 63;
    int beg = offsets[node], end = offsets[node + 1];
    float4 acc = {0.f, 0.f, 0.f, 0.f};
    if (H_BF16) {
        const u16* h = (const u16*)h_;
        for (int e = beg; e < end; ++e) {
            int dst = edgedst[e];
            ushort4 v = *(const ushort4*)(h + (size_t)dst * C + lane * 4);
            acc.x += bf2f(v.x); acc.y += bf2f(v.y);
            acc.z += bf2f(v.z); acc.w += bf2f(v.w);
        }
    } else {
        const float* h = (const float*)h_;
        for (int e = beg; e < end; ++e) {
            int dst = edgedst[e];
            float4 v = *(const float4*)(h + (size_t)dst * C + lane * 4);
            acc.x += v.x; acc.y += v.y; acc.z += v.z; acc.w += v.w;
        }
    }
    float inv = 1.0f / fmaxf((float)degcnt[node], 1.0f);
    ushort4 o;
    o.x = f2bf(acc.x * inv); o.y = f2bf(acc.y * inv);
    o.z = f2bf(acc.z * inv); o.w = f2bf(acc.w * inv);
    *(ushort4*)(aggb + (size_t)node * C + lane * 4) = o;
}

// ---- fused layer GEMM: [aggb | h | x0](64x768) @ Wcat^T -> relu -> LN -> bf16 ------
// block: 256 thr (4 waves, 2x2), tile M=64 x N=256 (full row in block), BK=32.
// aggb is bf16 (load_lds16); h is bf16 (B) or fp32 (A, reg-convert); x0 fp32 reg-convert.
template <bool H_BF16>
__global__ __launch_bounds__(256) void layer_gemm(
    const u16* __restrict__ Aagg,
    const void* __restrict__ Ah_, const float* __restrict__ Ax,
    const u16* __restrict__ W,    // [256][768] bf16
    const float* __restrict__ bcat,
    const float* __restrict__ lns, const float* __restrict__ lnb,
    u16* __restrict__ Hout, int Nnodes)
{
    __shared__ u16 Alds[64 * 32];    // [row][k], 4 KB
    __shared__ u16 Blds[256 * 32];   // [n][k], 16 KB
    __shared__ float lnpart[64][2][2];

    const int tid = threadIdx.x;
    const int wave = tid >> 6, lane = tid & 63;
    const int wave_m = wave & 1, wave_n = wave >> 1;
    const int q = lane >> 4, l15 = lane & 15;
    const int m0 = blockIdx.x * 64;

    int a_row  = wave * 16 + (lane >> 2);
    int a_node = m0 + a_row; if (a_node >= Nnodes) a_node = Nnodes - 1;
    const int kk8 = (lane & 3) * 8;
    const size_t a_off = (size_t)a_node * C + kk8;
    u16* AldsW = Alds + wave * 512;

    const u16* bg[4]; u16* bl[4];
    #pragma unroll
    for (int i = 0; i < 4; ++i) {
        int cb = wave * 4 + i;
        int n_row = cb * 16 + (lane >> 2);
        bg[i] = W + n_row * KCAT + kk8;
        bl[i] = Blds + cb * 512;
    }

    f32x4 acc[2][8] = {};

    for (int kt = 0; kt < 24; ++kt) {
        int k0 = kt * 32;
        const float* fsrc = nullptr;
        if (kt < 8) {
            load_lds16(Aagg + a_off + k0, AldsW);
        } else if (kt < 16) {
            if (H_BF16) load_lds16((const u16*)Ah_ + a_off + (k0 & 255), AldsW);
            else        fsrc = (const float*)Ah_ + a_off + (k0 & 255);
        } else {
            fsrc = Ax + a_off + (k0 & 255);
        }
        if (fsrc) {
            float4 v0 = *(const float4*)(fsrc);
            float4 v1 = *(const float4*)(fsrc + 4);
            u16x8 o;
            o[0] = f2bf(v0.x); o[1] = f2bf(v0.y); o[2] = f2bf(v0.z); o[3] = f2bf(v0.w);
            o[4] = f2bf(v1.x); o[5] = f2bf(v1.y); o[6] = f2bf(v1.z); o[7] = f2bf(v1.w);
            *(u16x8*)(AldsW + lane * 8) = o;    // lane*16B: same layout as load_lds16
        }
        #pragma unroll
        for (int i = 0; i < 4; ++i) load_lds16(bg[i] + k0, bl[i]);
        __syncthreads();

        bf16x8 af[2], bfr[8];
        #pragma unroll
        for (int t = 0; t < 2; ++t)
            af[t] = *(const bf16x8*)&Alds[(wave_m * 32 + t * 16 + l15) * 32 + q * 8];
        #pragma unroll
        for (int f = 0; f < 8; ++f)
            bfr[f] = *(const bf16x8*)&Blds[(wave_n * 128 + f * 16 + l15) * 32 + q * 8];
        #pragma unroll
        for (int t = 0; t < 2; ++t)
            #pragma unroll
            for (int f = 0; f < 8; ++f)
                acc[t][f] = __builtin_amdgcn_mfma_f32_16x16x32_bf16(af[t], bfr[f], acc[t][f], 0, 0, 0);
        __syncthreads();
    }

    // epilogue: +bias, relu, LayerNorm over 256 cols, write bf16
    float bias[8], lsc[8], lbi[8];
    #pragma unroll
    for (int f = 0; f < 8; ++f) {
        int n = wave_n * 128 + f * 16 + l15;
        bias[f] = bcat[n]; lsc[f] = lns[n]; lbi[f] = lnb[n];
    }
    float s1[2][4], s2[2][4];
    #pragma unroll
    for (int t = 0; t < 2; ++t)
        #pragma unroll
        for (int r = 0; r < 4; ++r) {
            float p = 0.f, pp = 0.f;
            #pragma unroll
            for (int f = 0; f < 8; ++f) {
                float v = acc[t][f][r] + bias[f];
                v = fmaxf(v, 0.f);
                acc[t][f][r] = v;
                p += v; pp += v * v;
            }
            #pragma unroll
            for (int off = 1; off < 16; off <<= 1) {
                p  += __shfl_xor(p,  off, 16);
                pp += __shfl_xor(pp, off, 16);
            }
            s1[t][r] = p; s2[t][r] = pp;
        }
    if (l15 == 0) {
        #pragma unroll
        for (int t = 0; t < 2; ++t)
            #pragma unroll
            for (int r = 0; r < 4; ++r) {
                int row = wave_m * 32 + t * 16 + q * 4 + r;
                lnpart[row][wave_n][0] = s1[t][r];
                lnpart[row][wave_n][1] = s2[t][r];
            }
    }
    __syncthreads();
    #pragma unroll
    for (int t = 0; t < 2; ++t)
        #pragma unroll
        for (int r = 0; r < 4; ++r) {
            int row = wave_m * 32 + t * 16 + q * 4 + r;
            int node = m0 + row;
            if (node < Nnodes) {
                float S1 = lnpart[row][0][0] + lnpart[row][1][0];
                float S2 = lnpart[row][0][1] + lnpart[row][1][1];
                float mean = S1 * (1.f / 256.f);
                float var  = S2 * (1.f / 256.f) - mean * mean;
                var = fmaxf(var, 0.f);
                float rstd = rsqrtf(var + LN_EPS);
                u16* op = Hout + (size_t)node * C;
                #pragma unroll
                for (int f = 0; f < 8; ++f) {
                    int n = wave_n * 128 + f * 16 + l15;
                    op[n] = f2bf((acc[t][f][r] - mean) * rstd * lsc[f] + lbi[f]);
                }
            }
        }
}

// ---- final GEMM: h2(bf16, in d_out) @ Woutb^T(128x256) + bout -> fp32, in place ----
__global__ __launch_bounds__(256) void final_gemm(
    const u16* __restrict__ A, const u16* __restrict__ W,
    const float* __restrict__ bout, float* __restrict__ out, int Nnodes)
{
    __shared__ u16 Alds[64 * 32];
    __shared__ u16 Blds[128 * 32];

    const int tid = threadIdx.x;
    const int wave = tid >> 6, lane = tid & 63;
    const int wave_m = wave & 1, wave_n = wave >> 1;
    const int q = lane >> 4, l15 = lane & 15;
    const int m0 = blockIdx.x * 64;

    int a_row  = wave * 16 + (lane >> 2);
    int a_node = m0 + a_row; if (a_node >= Nnodes) a_node = Nnodes - 1;
    const int kk8 = (lane & 3) * 8;
    const size_t a_off = (size_t)a_node * C + kk8;
    u16* AldsW = Alds + wave * 512;

    const u16* bg[2]; u16* bl[2];
    #pragma unroll
    for (int i = 0; i < 2; ++i) {
        int cb = wave * 2 + i;
        int n_row = cb * 16 + (lane >> 2);
        bg[i] = W + n_row * 256 + kk8;
        bl[i] = Blds + cb * 512;
    }

    f32x4 acc[2][4] = {};

    for (int kt = 0; kt < 8; ++kt) {
        int k0 = kt * 32;
        load_lds16(A + a_off + k0, AldsW);
        #pragma unroll
        for (int i = 0; i < 2; ++i) load_lds16(bg[i] + k0, bl[i]);
        __syncthreads();

        bf16x8 af[2], bfr[4];
        #pragma unroll
        for (int t = 0; t < 2; ++t)
            af[t] = *(const bf16x8*)&Alds[(wave_m * 32 + t * 16 + l15) * 32 + q * 8];
        #pragma unroll
        for (int f = 0; f < 4; ++f)
            bfr[f] = *(const bf16x8*)&Blds[(wave_n * 64 + f * 16 + l15) * 32 + q * 8];
        #pragma unroll
        for (int t = 0; t < 2; ++t)
            #pragma unroll
            for (int f = 0; f < 4; ++f)
                acc[t][f] = __builtin_amdgcn_mfma_f32_16x16x32_bf16(af[t], bfr[f], acc[t][f], 0, 0, 0);
        __syncthreads();
    }

    float bias[4];
    #pragma unroll
    for (int f = 0; f < 4; ++f) bias[f] = bout[wave_n * 64 + f * 16 + l15];
    #pragma unroll
    for (int t = 0; t < 2; ++t)
        #pragma unroll
        for (int r = 0; r < 4; ++r) {
            int row = wave_m * 32 + t * 16 + q * 4 + r;
            int node = m0 + row;
            if (node < Nnodes) {
                float* op = out + (size_t)node * OUTC;
                #pragma unroll
                for (int f = 0; f < 4; ++f) {
                    int n = wave_n * 64 + f * 16 + l15;
                    op[n] = acc[t][f][r] + bias[f];
                }
            }
        }
}

extern "C" void kernel_launch(void* const* d_in, const int* in_sizes, int n_in,
                              void* d_out, int out_size, void* d_ws, size_t ws_size,
                              hipStream_t stream)
{
    const float* x    = (const float*)d_in[0];
    const int*   ei0  = (const int*)d_in[1];
    const int*   ei1  = (const int*)d_in[2];
    const float* wl0  = (const float*)d_in[3];
    const float* bl0  = (const float*)d_in[4];
    const float* w00  = (const float*)d_in[5];
    const float* b00  = (const float*)d_in[6];
    const float* w10  = (const float*)d_in[7];
    const float* b10  = (const float*)d_in[8];
    const float* gate0= (const float*)d_in[9];
    const float* lns0 = (const float*)d_in[10];
    const float* lnb0 = (const float*)d_in[11];
    const float* wl1  = (const float*)d_in[12];
    const float* bl1  = (const float*)d_in[13];
    const float* w01  = (const float*)d_in[14];
    const float* b01  = (const float*)d_in[15];
    const float* w11  = (const float*)d_in[16];
    const float* b11  = (const float*)d_in[17];
    const float* gate1= (const float*)d_in[18];
    const float* lns1 = (const float*)d_in[19];
    const float* lnb1 = (const float*)d_in[20];
    const float* Wout = (const float*)d_in[21];
    const float* bout = (const float*)d_in[22];

    const int N = in_sizes[0] / C;     // 100000
    const int E = in_sizes[1] / 2;     // 400000

    // workspace (~109 MiB):
    char* w = (char*)d_ws;
    u16*   Wcat  = (u16*)w;   w += (size_t)2 * C * KCAT * 2;
    u16*   Woutb = (u16*)w;   w += (size_t)OUTC * C * 2;
    float* bcat  = (float*)w; w += 4096;
    int*   cnt1  = (int*)w;   w += (size_t)N * 4;       // counts -> cursor (graph ei1)
    int*   deg1  = (int*)w;   w += (size_t)N * 4;
    int*   cnt0  = (int*)w;   w += (size_t)N * 4;
    int*   deg0  = (int*)w;   w += (size_t)N * 4;       // 4 contiguous arrays, one memset
    int*   off1  = (int*)w;   w += (((size_t)(N + 1) * 4) + 255) & ~255ull;
    int*   off0  = (int*)w;   w += (((size_t)(N + 1) * 4) + 255) & ~255ull;
    int*   parts = (int*)w;   w += 4096;                // <=1024 block partials (reused)
    int*   ed1   = (int*)w;   w += (size_t)E * 4;
    int*   ed0   = (int*)w;   w += (size_t)E * 4;
    u16*   aggb  = (u16*)w;   w += (size_t)N * C * 2;   // 51.2 MB (reused both layers)
    u16*   h1    = (u16*)w;   w += (size_t)N * C * 2;   // 51.2 MB

    const int eb_grid = (E + 255) / 256;
    const int nblk    = (N + 255) / 256;                // 391 <= 1024
    const int gt_grid = (N + 3) / 4;
    const int gm_grid = (N + 63) / 64;
    u16* h2 = (u16*)d_out;   // layer-B bf16 output in d_out; final_gemm overwrites in place

    hipMemsetAsync(cnt1, 0, (size_t)4 * N * 4, stream);
    prep_weights<<<(2 * C * KCAT + OUTC * C) / 256, 256, 0, stream>>>(
        wl1, w01, w11, bl1, b01, b11, gate1,
        wl0, w00, w10, bl0, b00, b10, gate0,
        Wout, Wcat, bcat, Woutb);

    // ---- CSR builds (both graphs) ----
    count_edges<<<eb_grid, 256, 0, stream>>>(ei1, cnt1, deg1, E, N);
    count_edges<<<eb_grid, 256, 0, stream>>>(ei0, cnt0, deg0, E, N);
    block_sums<<<nblk, 256, 0, stream>>>(cnt1, parts, N);
    scan_partials<<<1, 1024, 0, stream>>>(parts, nblk);
    make_offsets<<<nblk, 256, 0, stream>>>(cnt1, parts, off1, N);
    fill_edges<<<eb_grid, 256, 0, stream>>>(ei1, cnt1, ed1, E, N);
    block_sums<<<nblk, 256, 0, stream>>>(cnt0, parts, N);
    scan_partials<<<1, 1024, 0, stream>>>(parts, nblk);
    make_offsets<<<nblk, 256, 0, stream>>>(cnt0, parts, off0, N);
    fill_edges<<<eb_grid, 256, 0, stream>>>(ei0, cnt0, ed0, E, N);

    // ---- layer A: graph ei1, params *1, h = x (fp32) ----
    gather_kernel<false><<<gt_grid, 256, 0, stream>>>(off1, ed1, deg1, x, aggb, N);
    layer_gemm<false><<<gm_grid, 256, 0, stream>>>(aggb, x, x, Wcat, bcat,
                                                   lns1, lnb1, h1, N);

    // ---- layer B: graph ei0, params *0, h = h1 (bf16) ----
    gather_kernel<true><<<gt_grid, 256, 0, stream>>>(off0, ed0, deg0, h1, aggb, N);
    layer_gemm<true><<<gm_grid, 256, 0, stream>>>(aggb, h1, x, Wcat + C * KCAT,
                                                  bcat + C, lns0, lnb0, h2, N);

    // ---- output projection (in place over d_out) ----
    final_gemm<<<gm_grid, 256, 0, stream>>>(h2, Woutb, bout, (float*)d_out, N);
}

// Round 5
// 592.303 us; speedup vs baseline: 5.2659x; 1.1110x over previous
//
#include <hip/hip_runtime.h>

typedef unsigned short u16;
typedef unsigned int   u32;

typedef __attribute__((ext_vector_type(8))) __bf16 bf16x8;
typedef __attribute__((ext_vector_type(8))) unsigned short u16x8;
typedef __attribute__((ext_vector_type(4))) float  f32x4;

#define C      256
#define OUTC   128
#define LN_EPS 1e-5f

__device__ __forceinline__ float bf2f(u16 u) {
    u32 i = ((u32)u) << 16; float f; __builtin_memcpy(&f, &i, 4); return f;
}
__device__ __forceinline__ u16 f2bf(float f) {
    u32 i; __builtin_memcpy(&i, &f, 4);
    u32 r = (i + 0x7FFFu + ((i >> 16) & 1u)) >> 16;
    return (u16)r;
}
__device__ __forceinline__ void load_lds16(const void* g, void* l) {
    __builtin_amdgcn_global_load_lds((const __attribute__((address_space(1))) u32*)g,
                                     (__attribute__((address_space(3))) u32*)l, 16, 0, 0);
}
// XOR chunk swizzle: row r's 4 16B-chunks are stored permuted so that strided
// fragment reads (row stride 64B) spread across bank groups (2-way max).
__device__ __forceinline__ int swz(int row) { return (row + (row >> 2)) & 3; }

// ---- x (fp32) -> xb (bf16), one pass --------------------------------------------
__global__ void xcast_kernel(const float* __restrict__ x, u16* __restrict__ xb, size_t n8)
{
    size_t i = ((size_t)blockIdx.x * 256 + threadIdx.x);
    if (i >= n8) return;
    const float* p = x + i * 8;
    float4 v0 = *(const float4*)p;
    float4 v1 = *(const float4*)(p + 4);
    u16x8 o;
    o[0] = f2bf(v0.x); o[1] = f2bf(v0.y); o[2] = f2bf(v0.z); o[3] = f2bf(v0.w);
    o[4] = f2bf(v1.x); o[5] = f2bf(v1.y); o[6] = f2bf(v1.z); o[7] = f2bf(v1.w);
    *(u16x8*)(xb + i * 8) = o;
}

// ---- weight prep: WcatA[256][512] (layer A: h==x0 -> fold w0,w1), WcatB[256][768],
//      Woutb[128][256] bf16; bcat[2][256] fp32 ------------------------------------
__global__ void prep_weights(const float* wl0, const float* w00, const float* w10,
                             const float* bl0, const float* b00, const float* b10,
                             const float* gate0,
                             const float* wl1, const float* w01, const float* w11,
                             const float* bl1, const float* b01, const float* b11,
                             const float* gate1,
                             const float* Wout,
                             u16* __restrict__ WcatA, u16* __restrict__ WcatB,
                             u16* __restrict__ Woutb, float* __restrict__ bcat)
{
    int idx = blockIdx.x * 256 + threadIdx.x;
    float gA = 1.f / (1.f + expf(-gate1[0]));   // layer processed FIRST uses params *1
    float gB = 1.f / (1.f + expf(-gate0[0]));
    if (idx < 256 * 512) {
        int n = idx >> 9, k = idx & 511;
        float v;
        if (k < 256) v = wl1[n * 256 + k];
        else         v = (1.f - gA) * w01[n * 256 + (k - 256)] + gA * w11[n * 256 + (k - 256)];
        WcatA[idx] = f2bf(v);
    } else if (idx < 256 * 512 + 256 * 768) {
        int j = idx - 256 * 512;
        int n = j / 768, k = j - n * 768;
        float v;
        if (k < 256)      v = wl0[n * 256 + k];
        else if (k < 512) v = (1.f - gB) * w00[n * 256 + (k - 256)];
        else              v = gB * w10[n * 256 + (k - 512)];
        WcatB[j] = f2bf(v);
    } else {
        int j = idx - (256 * 512 + 256 * 768);
        if (j < OUTC * C) Woutb[j] = f2bf(Wout[j]);
    }
    if (idx < 512) {
        int nn = idx & 255;
        if (idx < 256) bcat[idx] = bl1[nn] + (1.f - gA) * b01[nn] + gA * b11[nn];
        else           bcat[idx] = bl0[nn] + (1.f - gB) * b00[nn] + gB * b10[nn];
    }
}

// ================= CSR build ======================================================
__global__ void count_edges(const int* __restrict__ ei, int* __restrict__ counts,
                            int* __restrict__ degcnt, int E, int Nn)
{
    int idx = blockIdx.x * 256 + threadIdx.x;
    if (idx >= E) return;
    int s = ei[idx], d = ei[E + idx];
    if ((unsigned)s >= (unsigned)Nn || (unsigned)d >= (unsigned)Nn) return;
    atomicAdd(counts + s, 1);
    atomicAdd(degcnt + d, 1);
}

__global__ void block_sums(const int* __restrict__ counts, int* __restrict__ partials, int n)
{
    int i = blockIdx.x * 256 + threadIdx.x;
    int v = (i < n) ? counts[i] : 0;
    #pragma unroll
    for (int off = 32; off; off >>= 1) v += __shfl_down(v, off, 64);
    __shared__ int ws[4];
    if ((threadIdx.x & 63) == 0) ws[threadIdx.x >> 6] = v;
    __syncthreads();
    if (threadIdx.x == 0) partials[blockIdx.x] = ws[0] + ws[1] + ws[2] + ws[3];
}

__global__ void scan_partials(int* __restrict__ partials, int nblk)
{
    __shared__ int buf[1024];
    int tid = threadIdx.x;
    int v = (tid < nblk) ? partials[tid] : 0;
    buf[tid] = v; __syncthreads();
    for (int off = 1; off < 1024; off <<= 1) {
        int t = (tid >= off) ? buf[tid - off] : 0;
        __syncthreads();
        buf[tid] += t;
        __syncthreads();
    }
    if (tid < nblk) partials[tid] = buf[tid] - v;
}

__global__ void make_offsets(int* __restrict__ counts_cursor, const int* __restrict__ partials,
                             int* __restrict__ offsets, int n)
{
    __shared__ int buf[256];
    int i = blockIdx.x * 256 + threadIdx.x;
    int cnt = (i < n) ? counts_cursor[i] : 0;
    buf[threadIdx.x] = cnt; __syncthreads();
    for (int off = 1; off < 256; off <<= 1) {
        int t = (threadIdx.x >= off) ? buf[threadIdx.x - off] : 0;
        __syncthreads();
        buf[threadIdx.x] += t;
        __syncthreads();
    }
    int off = partials[blockIdx.x] + buf[threadIdx.x] - cnt;
    if (i < n) {
        offsets[i] = off;
        counts_cursor[i] = off;
        if (i == n - 1) offsets[n] = off + cnt;
    }
}

__global__ void fill_edges(const int* __restrict__ ei, int* __restrict__ cursor,
                           int* __restrict__ edgedst, int E, int Nn)
{
    int idx = blockIdx.x * 256 + threadIdx.x;
    if (idx >= E) return;
    int s = ei[idx], d = ei[E + idx];
    if ((unsigned)s >= (unsigned)Nn || (unsigned)d >= (unsigned)Nn) return;
    int p = atomicAdd(cursor + s, 1);
    edgedst[p] = d;
}

// ---- gather: one wave per node; aggb[i] = (1/clip(deg,1)) * sum_{CSR[i]} h[dst] ----
__global__ __launch_bounds__(256) void gather_kernel(
    const int* __restrict__ offsets, const int* __restrict__ edgedst,
    const int* __restrict__ degcnt, const u16* __restrict__ h,
    u16* __restrict__ aggb, int Nn)
{
    int node = blockIdx.x * 4 + (threadIdx.x >> 6);
    if (node >= Nn) return;
    int lane = threadIdx.x & 63;
    int beg = offsets[node], end = offsets[node + 1];
    float4 acc = {0.f, 0.f, 0.f, 0.f};
    for (int e = beg; e < end; ++e) {
        int dst = edgedst[e];
        ushort4 v = *(const ushort4*)(h + (size_t)dst * C + lane * 4);
        acc.x += bf2f(v.x); acc.y += bf2f(v.y);
        acc.z += bf2f(v.z); acc.w += bf2f(v.w);
    }
    float inv = 1.0f / fmaxf((float)degcnt[node], 1.0f);
    ushort4 o;
    o.x = f2bf(acc.x * inv); o.y = f2bf(acc.y * inv);
    o.z = f2bf(acc.z * inv); o.w = f2bf(acc.w * inv);
    *(ushort4*)(aggb + (size_t)node * C + lane * 4) = o;
}

// ---- fused layer GEMM: [s0|s1(|s2)](128 x NSEG*256) @ W^T -> +bias, relu, LN -> bf16
// 512 thr = 8 waves (2 m-halves x 4 n-quarters), tile M=128 x N=256, BK=32.
// All segments bf16, staged with swizzled global_load_lds (2-way max LDS conflicts).
template <int NSEG>
__global__ __launch_bounds__(512, 4) void layer_gemm(
    const u16* __restrict__ s0, const u16* __restrict__ s1, const u16* __restrict__ s2,
    const u16* __restrict__ W,          // [256][NSEG*256] bf16
    const float* __restrict__ bcat,
    const float* __restrict__ lns, const float* __restrict__ lnb,
    u16* __restrict__ Hout, int Nnodes)
{
    constexpr int WK = NSEG * 256;
    constexpr int KT = NSEG * 8;

    __shared__ u16 Alds[128 * 32];        // 8 KB: [row][k] with swizzled 16B chunks
    __shared__ u16 Blds[256 * 32];        // 16 KB
    __shared__ float lnpart[128][4][2];   // 4 KB

    const int tid  = threadIdx.x;
    const int wave = tid >> 6, lane = tid & 63;
    const int wave_m = wave & 1, wave_n = wave >> 1;   // 2 x 4
    const int q = lane >> 4, l15 = lane & 15;
    const int m0 = blockIdx.x * 128;

    // ---- staging addresses (computed once) ----
    // A: wave stages chunk `wave` (16 rows). lane -> (row = wave*16 + lane/4,
    // stored-chunk cs = lane&3, actual chunk = cs ^ swz(row)).
    const int srow = (wave << 4) + (lane >> 2);
    int anode = m0 + srow; if (anode >= Nnodes) anode = Nnodes - 1;
    const int asc = (lane & 3) ^ swz(srow);
    const size_t a_goff = (size_t)anode * C + asc * 8;
    u16* a_ldst = Alds + (wave << 9);

    // B: wave stages chunks {wave, wave+8}
    const u16* bgp[2]; u16* bldst[2];
    #pragma unroll
    for (int i = 0; i < 2; ++i) {
        int cb = wave + i * 8;
        int brow = (cb << 4) + (lane >> 2);
        int bsc = (lane & 3) ^ swz(brow);
        bgp[i]   = W + brow * WK + bsc * 8;
        bldst[i] = Blds + (cb << 9);
    }

    // ---- fragment LDS offsets (u16 units) ----
    int aoff[4], boff[4];
    #pragma unroll
    for (int t = 0; t < 4; ++t) {
        int ar = wave_m * 64 + t * 16 + l15;
        aoff[t] = ar * 32 + ((q ^ swz(ar)) << 3);
        int br = wave_n * 64 + t * 16 + l15;
        boff[t] = br * 32 + ((q ^ swz(br)) << 3);
    }

    f32x4 acc[4][4] = {};

    for (int kt = 0; kt < KT; ++kt) {
        const u16* Asrc = (kt < 8) ? s0 : ((NSEG == 2 || kt < 16) ? s1 : s2);
        load_lds16(Asrc + a_goff + ((kt & 7) << 5), a_ldst);
        int k0 = kt << 5;
        load_lds16(bgp[0] + k0, bldst[0]);
        load_lds16(bgp[1] + k0, bldst[1]);
        __syncthreads();

        bf16x8 af[4], bfr[4];
        #pragma unroll
        for (int t = 0; t < 4; ++t) af[t]  = *(const bf16x8*)&Alds[aoff[t]];
        #pragma unroll
        for (int f = 0; f < 4; ++f) bfr[f] = *(const bf16x8*)&Blds[boff[f]];
        #pragma unroll
        for (int t = 0; t < 4; ++t)
            #pragma unroll
            for (int f = 0; f < 4; ++f)
                acc[t][f] = __builtin_amdgcn_mfma_f32_16x16x32_bf16(af[t], bfr[f], acc[t][f], 0, 0, 0);
        __syncthreads();
    }

    // ---- epilogue: +bias, relu, LN over 256 cols, write bf16 ----
    float bias[4], lsc[4], lbi[4];
    #pragma unroll
    for (int f = 0; f < 4; ++f) {
        int n = wave_n * 64 + f * 16 + l15;
        bias[f] = bcat[n]; lsc[f] = lns[n]; lbi[f] = lnb[n];
    }
    #pragma unroll
    for (int t = 0; t < 4; ++t)
        #pragma unroll
        for (int r = 0; r < 4; ++r) {
            float p = 0.f, pp = 0.f;
            #pragma unroll
            for (int f = 0; f < 4; ++f) {
                float v = acc[t][f][r] + bias[f];
                v = fmaxf(v, 0.f);
                acc[t][f][r] = v;
                p += v; pp += v * v;
            }
            #pragma unroll
            for (int off = 1; off < 16; off <<= 1) {
                p  += __shfl_xor(p,  off, 16);
                pp += __shfl_xor(pp, off, 16);
            }
            if (l15 == 0) {
                int row = wave_m * 64 + t * 16 + q * 4 + r;
                lnpart[row][wave_n][0] = p;
                lnpart[row][wave_n][1] = pp;
            }
        }
    __syncthreads();
    #pragma unroll
    for (int t = 0; t < 4; ++t)
        #pragma unroll
        for (int r = 0; r < 4; ++r) {
            int row = wave_m * 64 + t * 16 + q * 4 + r;
            int node = m0 + row;
            if (node < Nnodes) {
                float S1 = lnpart[row][0][0] + lnpart[row][1][0]
                         + lnpart[row][2][0] + lnpart[row][3][0];
                float S2 = lnpart[row][0][1] + lnpart[row][1][1]
                         + lnpart[row][2][1] + lnpart[row][3][1];
                float mean = S1 * (1.f / 256.f);
                float var  = fmaxf(S2 * (1.f / 256.f) - mean * mean, 0.f);
                float rstd = rsqrtf(var + LN_EPS);
                u16* op = Hout + (size_t)node * C;
                #pragma unroll
                for (int f = 0; f < 4; ++f) {
                    int n = wave_n * 64 + f * 16 + l15;
                    op[n] = f2bf((acc[t][f][r] - mean) * rstd * lsc[f] + lbi[f]);
                }
            }
        }
}

// ---- final GEMM: h2(bf16, in d_out) @ Woutb^T(128x256) + bout -> fp32, in place ----
__global__ __launch_bounds__(256) void final_gemm(
    const u16* __restrict__ A, const u16* __restrict__ W,
    const float* __restrict__ bout, float* __restrict__ out, int Nnodes)
{
    __shared__ u16 Alds[64 * 32];
    __shared__ u16 Blds[128 * 32];

    const int tid = threadIdx.x;
    const int wave = tid >> 6, lane = tid & 63;
    const int wave_m = wave & 1, wave_n = wave >> 1;
    const int q = lane >> 4, l15 = lane & 15;
    const int m0 = blockIdx.x * 64;

    int a_row  = wave * 16 + (lane >> 2);
    int a_node = m0 + a_row; if (a_node >= Nnodes) a_node = Nnodes - 1;
    const int kk8 = (lane & 3) * 8;
    const size_t a_off = (size_t)a_node * C + kk8;
    u16* AldsW = Alds + wave * 512;

    const u16* bg[2]; u16* bl[2];
    #pragma unroll
    for (int i = 0; i < 2; ++i) {
        int cb = wave * 2 + i;
        int n_row = cb * 16 + (lane >> 2);
        bg[i] = W + n_row * 256 + kk8;
        bl[i] = Blds + cb * 512;
    }

    f32x4 acc[2][4] = {};

    for (int kt = 0; kt < 8; ++kt) {
        int k0 = kt * 32;
        load_lds16(A + a_off + k0, AldsW);
        #pragma unroll
        for (int i = 0; i < 2; ++i) load_lds16(bg[i] + k0, bl[i]);
        __syncthreads();

        bf16x8 af[2], bfr[4];
        #pragma unroll
        for (int t = 0; t < 2; ++t)
            af[t] = *(const bf16x8*)&Alds[(wave_m * 32 + t * 16 + l15) * 32 + q * 8];
        #pragma unroll
        for (int f = 0; f < 4; ++f)
            bfr[f] = *(const bf16x8*)&Blds[(wave_n * 64 + f * 16 + l15) * 32 + q * 8];
        #pragma unroll
        for (int t = 0; t < 2; ++t)
            #pragma unroll
            for (int f = 0; f < 4; ++f)
                acc[t][f] = __builtin_amdgcn_mfma_f32_16x16x32_bf16(af[t], bfr[f], acc[t][f], 0, 0, 0);
        __syncthreads();
    }

    float bias[4];
    #pragma unroll
    for (int f = 0; f < 4; ++f) bias[f] = bout[wave_n * 64 + f * 16 + l15];
    #pragma unroll
    for (int t = 0; t < 2; ++t)
        #pragma unroll
        for (int r = 0; r < 4; ++r) {
            int row = wave_m * 32 + t * 16 + q * 4 + r;
            int node = m0 + row;
            if (node < Nnodes) {
                float* op = out + (size_t)node * OUTC;
                #pragma unroll
                for (int f = 0; f < 4; ++f) {
                    int n = wave_n * 64 + f * 16 + l15;
                    op[n] = acc[t][f][r] + bias[f];
                }
            }
        }
}

extern "C" void kernel_launch(void* const* d_in, const int* in_sizes, int n_in,
                              void* d_out, int out_size, void* d_ws, size_t ws_size,
                              hipStream_t stream)
{
    const float* x    = (const float*)d_in[0];
    const int*   ei0  = (const int*)d_in[1];
    const int*   ei1  = (const int*)d_in[2];
    const float* wl0  = (const float*)d_in[3];
    const float* bl0  = (const float*)d_in[4];
    const float* w00  = (const float*)d_in[5];
    const float* b00  = (const float*)d_in[6];
    const float* w10  = (const float*)d_in[7];
    const float* b10  = (const float*)d_in[8];
    const float* gate0= (const float*)d_in[9];
    const float* lns0 = (const float*)d_in[10];
    const float* lnb0 = (const float*)d_in[11];
    const float* wl1  = (const float*)d_in[12];
    const float* bl1  = (const float*)d_in[13];
    const float* w01  = (const float*)d_in[14];
    const float* b01  = (const float*)d_in[15];
    const float* w11  = (const float*)d_in[16];
    const float* b11  = (const float*)d_in[17];
    const float* gate1= (const float*)d_in[18];
    const float* lns1 = (const float*)d_in[19];
    const float* lnb1 = (const float*)d_in[20];
    const float* Wout = (const float*)d_in[21];
    const float* bout = (const float*)d_in[22];

    const int N = in_sizes[0] / C;     // 100000
    const int E = in_sizes[1] / 2;     // 400000

    // workspace (~161 MiB)
    char* w = (char*)d_ws;
    u16*   WcatA = (u16*)w;   w += (size_t)256 * 512 * 2;
    u16*   WcatB = (u16*)w;   w += (size_t)256 * 768 * 2;
    u16*   Woutb = (u16*)w;   w += (size_t)OUTC * C * 2;
    float* bcat  = (float*)w; w += 4096;
    int*   cnt1  = (int*)w;   w += (size_t)N * 4;       // 4 contiguous, one memset
    int*   deg1  = (int*)w;   w += (size_t)N * 4;
    int*   cnt0  = (int*)w;   w += (size_t)N * 4;
    int*   deg0  = (int*)w;   w += (size_t)N * 4;
    int*   off1  = (int*)w;   w += (((size_t)(N + 1) * 4) + 255) & ~255ull;
    int*   off0  = (int*)w;   w += (((size_t)(N + 1) * 4) + 255) & ~255ull;
    int*   parts = (int*)w;   w += 4096;
    int*   ed1   = (int*)w;   w += (size_t)E * 4;
    int*   ed0   = (int*)w;   w += (size_t)E * 4;
    u16*   xb    = (u16*)w;   w += (size_t)N * C * 2;   // 51.2 MB bf16 copy of x
    u16*   aggb  = (u16*)w;   w += (size_t)N * C * 2;   // 51.2 MB (reused both layers)
    u16*   h1    = (u16*)w;   w += (size_t)N * C * 2;   // 51.2 MB

    const int eb_grid = (E + 255) / 256;
    const int nblk    = (N + 255) / 256;                // 391 <= 1024
    const int gt_grid = (N + 3) / 4;
    const int gm_grid = (N + 127) / 128;
    const int fg_grid = (N + 63) / 64;
    u16* h2 = (u16*)d_out;   // layer-B bf16 output in d_out; final_gemm overwrites in place

    hipMemsetAsync(cnt1, 0, (size_t)4 * N * 4, stream);
    prep_weights<<<(256 * 512 + 256 * 768 + OUTC * C) / 256, 256, 0, stream>>>(
        wl0, w00, w10, bl0, b00, b10, gate0,
        wl1, w01, w11, bl1, b01, b11, gate1,
        Wout, WcatA, WcatB, Woutb, bcat);
    xcast_kernel<<<(int)(((size_t)N * C / 8 + 255) / 256), 256, 0, stream>>>(
        x, xb, (size_t)N * C / 8);

    // ---- CSR builds (both graphs) ----
    count_edges<<<eb_grid, 256, 0, stream>>>(ei1, cnt1, deg1, E, N);
    count_edges<<<eb_grid, 256, 0, stream>>>(ei0, cnt0, deg0, E, N);
    block_sums<<<nblk, 256, 0, stream>>>(cnt1, parts, N);
    scan_partials<<<1, 1024, 0, stream>>>(parts, nblk);
    make_offsets<<<nblk, 256, 0, stream>>>(cnt1, parts, off1, N);
    fill_edges<<<eb_grid, 256, 0, stream>>>(ei1, cnt1, ed1, E, N);
    block_sums<<<nblk, 256, 0, stream>>>(cnt0, parts, N);
    scan_partials<<<1, 1024, 0, stream>>>(parts, nblk);
    make_offsets<<<nblk, 256, 0, stream>>>(cnt0, parts, off0, N);
    fill_edges<<<eb_grid, 256, 0, stream>>>(ei0, cnt0, ed0, E, N);

    // ---- layer A: graph ei1, params *1, h = x0 = xb; K = 512 (w0,w1 folded) ----
    gather_kernel<<<gt_grid, 256, 0, stream>>>(off1, ed1, deg1, xb, aggb, N);
    layer_gemm<2><<<gm_grid, 512, 0, stream>>>(aggb, xb, nullptr, WcatA, bcat,
                                               lns1, lnb1, h1, N);

    // ---- layer B: graph ei0, params *0, h = h1, x0 = xb; K = 768 ----
    gather_kernel<<<gt_grid, 256, 0, stream>>>(off0, ed0, deg0, h1, aggb, N);
    layer_gemm<3><<<gm_grid, 512, 0, stream>>>(aggb, h1, xb, WcatB, bcat + C,
                                               lns0, lnb0, h2, N);

    // ---- output projection (in place over d_out) ----
    final_gemm<<<fg_grid, 256, 0, stream>>>(h2, Woutb, bout, (float*)d_out, N);
}

// Round 6
// 556.714 us; speedup vs baseline: 5.6025x; 1.0639x over previous
//
#include <hip/hip_runtime.h>

typedef unsigned short u16;
typedef unsigned int   u32;

typedef __attribute__((ext_vector_type(8))) __bf16 bf16x8;
typedef __attribute__((ext_vector_type(8))) unsigned short u16x8;
typedef __attribute__((ext_vector_type(4))) float  f32x4;

#define C      256
#define OUTC   128
#define LN_EPS 1e-5f

__device__ __forceinline__ float bf2f(u16 u) {
    u32 i = ((u32)u) << 16; float f; __builtin_memcpy(&f, &i, 4); return f;
}
__device__ __forceinline__ u16 f2bf(float f) {
    u32 i; __builtin_memcpy(&i, &f, 4);
    u32 r = (i + 0x7FFFu + ((i >> 16) & 1u)) >> 16;
    return (u16)r;
}
__device__ __forceinline__ void load_lds16(const void* g, void* l) {
    __builtin_amdgcn_global_load_lds((const __attribute__((address_space(1))) u32*)g,
                                     (__attribute__((address_space(3))) u32*)l, 16, 0, 0);
}
// XOR chunk swizzle: row r's 4 16B-chunks stored permuted so strided fragment
// reads (row stride 64B) spread across bank groups.
__device__ __forceinline__ int swz(int row) { return (row + (row >> 2)) & 3; }

// ---- combined prep: weights (blocks < PREP_BLK) + x->bf16 cast (rest) ------------
#define PREP_BLK 1408   // (256*512 + 256*768 + 128*256) / 256
__global__ void prep_combo(const float* wl0, const float* w00, const float* w10,
                           const float* bl0, const float* b00, const float* b10,
                           const float* gate0,
                           const float* wl1, const float* w01, const float* w11,
                           const float* bl1, const float* b01, const float* b11,
                           const float* gate1,
                           const float* Wout, const float* x,
                           u16* __restrict__ WcatA, u16* __restrict__ WcatB,
                           u16* __restrict__ Woutb, float* __restrict__ bcat,
                           u16* __restrict__ xb, size_t n8)
{
    if (blockIdx.x >= PREP_BLK) {
        size_t i = ((size_t)(blockIdx.x - PREP_BLK) * 256 + threadIdx.x);
        if (i >= n8) return;
        const float* p = x + i * 8;
        float4 v0 = *(const float4*)p;
        float4 v1 = *(const float4*)(p + 4);
        u16x8 o;
        o[0] = f2bf(v0.x); o[1] = f2bf(v0.y); o[2] = f2bf(v0.z); o[3] = f2bf(v0.w);
        o[4] = f2bf(v1.x); o[5] = f2bf(v1.y); o[6] = f2bf(v1.z); o[7] = f2bf(v1.w);
        *(u16x8*)(xb + i * 8) = o;
        return;
    }
    int idx = blockIdx.x * 256 + threadIdx.x;
    float gA = 1.f / (1.f + expf(-gate1[0]));   // layer processed FIRST uses params *1
    float gB = 1.f / (1.f + expf(-gate0[0]));
    if (idx < 256 * 512) {
        int n = idx >> 9, k = idx & 511;
        float v;
        if (k < 256) v = wl1[n * 256 + k];
        else         v = (1.f - gA) * w01[n * 256 + (k - 256)] + gA * w11[n * 256 + (k - 256)];
        WcatA[idx] = f2bf(v);
    } else if (idx < 256 * 512 + 256 * 768) {
        int j = idx - 256 * 512;
        int n = j / 768, k = j - n * 768;
        float v;
        if (k < 256)      v = wl0[n * 256 + k];
        else if (k < 512) v = (1.f - gB) * w00[n * 256 + (k - 256)];
        else              v = gB * w10[n * 256 + (k - 512)];
        WcatB[j] = f2bf(v);
    } else {
        int j = idx - (256 * 512 + 256 * 768);
        if (j < OUTC * C) Woutb[j] = f2bf(Wout[j]);
    }
    if (idx < 512) {
        int nn = idx & 255;
        if (idx < 256) bcat[idx] = bl1[nn] + (1.f - gA) * b01[nn] + gA * b11[nn];
        else           bcat[idx] = bl0[nn] + (1.f - gB) * b00[nn] + gB * b10[nn];
    }
}

// ================= CSR build (both graphs per launch) =============================
__global__ void count_edges2(const int* __restrict__ ei1, const int* __restrict__ ei0,
                             int* __restrict__ cnt1, int* __restrict__ deg1,
                             int* __restrict__ cnt0, int* __restrict__ deg0,
                             int E, int Nn, int ebg)
{
    int b = blockIdx.x;
    const int* ei; int *cnt, *deg;
    if (b < ebg) { ei = ei1; cnt = cnt1; deg = deg1; }
    else         { b -= ebg; ei = ei0; cnt = cnt0; deg = deg0; }
    int idx = b * 256 + threadIdx.x;
    if (idx >= E) return;
    int s = ei[idx], d = ei[E + idx];
    if ((unsigned)s >= (unsigned)Nn || (unsigned)d >= (unsigned)Nn) return;
    atomicAdd(cnt + s, 1);
    atomicAdd(deg + d, 1);
}

__global__ void block_sums2(const int* __restrict__ cnt1, const int* __restrict__ cnt0,
                            int* __restrict__ parts1, int* __restrict__ parts0,
                            int n, int nblk)
{
    int b = blockIdx.x;
    const int* counts; int* partials;
    if (b < nblk) { counts = cnt1; partials = parts1; }
    else          { b -= nblk; counts = cnt0; partials = parts0; }
    int i = b * 256 + threadIdx.x;
    int v = (i < n) ? counts[i] : 0;
    #pragma unroll
    for (int off = 32; off; off >>= 1) v += __shfl_down(v, off, 64);
    __shared__ int ws[4];
    if ((threadIdx.x & 63) == 0) ws[threadIdx.x >> 6] = v;
    __syncthreads();
    if (threadIdx.x == 0) partials[b] = ws[0] + ws[1] + ws[2] + ws[3];
}

__global__ void scan_partials2(int* __restrict__ parts1, int* __restrict__ parts0, int nblk)
{
    int* partials = blockIdx.x ? parts0 : parts1;
    __shared__ int buf[1024];
    int tid = threadIdx.x;
    int v = (tid < nblk) ? partials[tid] : 0;
    buf[tid] = v; __syncthreads();
    for (int off = 1; off < 1024; off <<= 1) {
        int t = (tid >= off) ? buf[tid - off] : 0;
        __syncthreads();
        buf[tid] += t;
        __syncthreads();
    }
    if (tid < nblk) partials[tid] = buf[tid] - v;
}

__global__ void make_offsets2(int* __restrict__ cnt1, int* __restrict__ cnt0,
                              const int* __restrict__ parts1, const int* __restrict__ parts0,
                              int* __restrict__ off1a, int* __restrict__ off0a,
                              int n, int nblk)
{
    int b = blockIdx.x;
    int* counts_cursor; const int* partials; int* offsets;
    if (b < nblk) { counts_cursor = cnt1; partials = parts1; offsets = off1a; }
    else          { b -= nblk; counts_cursor = cnt0; partials = parts0; offsets = off0a; }
    __shared__ int buf[256];
    int i = b * 256 + threadIdx.x;
    int cnt = (i < n) ? counts_cursor[i] : 0;
    buf[threadIdx.x] = cnt; __syncthreads();
    for (int off = 1; off < 256; off <<= 1) {
        int t = (threadIdx.x >= off) ? buf[threadIdx.x - off] : 0;
        __syncthreads();
        buf[threadIdx.x] += t;
        __syncthreads();
    }
    int off = partials[b] + buf[threadIdx.x] - cnt;
    if (i < n) {
        offsets[i] = off;
        counts_cursor[i] = off;
        if (i == n - 1) offsets[n] = off + cnt;
    }
}

__global__ void fill_edges2(const int* __restrict__ ei1, const int* __restrict__ ei0,
                            int* __restrict__ cur1, int* __restrict__ cur0,
                            int* __restrict__ ed1, int* __restrict__ ed0,
                            int E, int Nn, int ebg)
{
    int b = blockIdx.x;
    const int* ei; int *cursor, *edgedst;
    if (b < ebg) { ei = ei1; cursor = cur1; edgedst = ed1; }
    else         { b -= ebg; ei = ei0; cursor = cur0; edgedst = ed0; }
    int idx = b * 256 + threadIdx.x;
    if (idx >= E) return;
    int s = ei[idx], d = ei[E + idx];
    if ((unsigned)s >= (unsigned)Nn || (unsigned)d >= (unsigned)Nn) return;
    int p = atomicAdd(cursor + s, 1);
    edgedst[p] = d;
}

// ---- gather: one wave per node; 2-edge unroll (dual accumulators for MLP) --------
__global__ __launch_bounds__(256) void gather_kernel(
    const int* __restrict__ offsets, const int* __restrict__ edgedst,
    const int* __restrict__ degcnt, const u16* __restrict__ h,
    u16* __restrict__ aggb, int Nn)
{
    int node = blockIdx.x * 4 + (threadIdx.x >> 6);
    if (node >= Nn) return;
    int lane = threadIdx.x & 63;
    int beg = offsets[node], end = offsets[node + 1];
    float4 a0 = {0.f, 0.f, 0.f, 0.f}, a1 = {0.f, 0.f, 0.f, 0.f};
    int e = beg;
    for (; e + 1 < end; e += 2) {
        int d0 = edgedst[e], d1 = edgedst[e + 1];
        ushort4 v0 = *(const ushort4*)(h + (size_t)d0 * C + lane * 4);
        ushort4 v1 = *(const ushort4*)(h + (size_t)d1 * C + lane * 4);
        a0.x += bf2f(v0.x); a0.y += bf2f(v0.y); a0.z += bf2f(v0.z); a0.w += bf2f(v0.w);
        a1.x += bf2f(v1.x); a1.y += bf2f(v1.y); a1.z += bf2f(v1.z); a1.w += bf2f(v1.w);
    }
    if (e < end) {
        int d0 = edgedst[e];
        ushort4 v0 = *(const ushort4*)(h + (size_t)d0 * C + lane * 4);
        a0.x += bf2f(v0.x); a0.y += bf2f(v0.y); a0.z += bf2f(v0.z); a0.w += bf2f(v0.w);
    }
    float inv = 1.0f / fmaxf((float)degcnt[node], 1.0f);
    ushort4 o;
    o.x = f2bf((a0.x + a1.x) * inv); o.y = f2bf((a0.y + a1.y) * inv);
    o.z = f2bf((a0.z + a1.z) * inv); o.w = f2bf((a0.w + a1.w) * inv);
    *(ushort4*)(aggb + (size_t)node * C + lane * 4) = o;
}

// ---- fused layer GEMM: [s0|s1(|s2)](128 x NSEG*256) @ W^T -> +bias, relu, LN -> bf16
template <int NSEG>
__global__ __launch_bounds__(512, 4) void layer_gemm(
    const u16* __restrict__ s0, const u16* __restrict__ s1, const u16* __restrict__ s2,
    const u16* __restrict__ W,          // [256][NSEG*256] bf16
    const float* __restrict__ bcat,
    const float* __restrict__ lns, const float* __restrict__ lnb,
    u16* __restrict__ Hout, int Nnodes)
{
    constexpr int WK = NSEG * 256;
    constexpr int KT = NSEG * 8;

    __shared__ u16 Alds[128 * 32];        // 8 KB
    __shared__ u16 Blds[256 * 32];        // 16 KB
    __shared__ float lnpart[128][4][2];   // 4 KB

    const int tid  = threadIdx.x;
    const int wave = tid >> 6, lane = tid & 63;
    const int wave_m = wave & 1, wave_n = wave >> 1;   // 2 x 4
    const int q = lane >> 4, l15 = lane & 15;
    const int m0 = blockIdx.x * 128;

    const int srow = (wave << 4) + (lane >> 2);
    int anode = m0 + srow; if (anode >= Nnodes) anode = Nnodes - 1;
    const int asc = (lane & 3) ^ swz(srow);
    const size_t a_goff = (size_t)anode * C + asc * 8;
    u16* a_ldst = Alds + (wave << 9);

    const u16* bgp[2]; u16* bldst[2];
    #pragma unroll
    for (int i = 0; i < 2; ++i) {
        int cb = wave + i * 8;
        int brow = (cb << 4) + (lane >> 2);
        int bsc = (lane & 3) ^ swz(brow);
        bgp[i]   = W + brow * WK + bsc * 8;
        bldst[i] = Blds + (cb << 9);
    }

    int aoff[4], boff[4];
    #pragma unroll
    for (int t = 0; t < 4; ++t) {
        int ar = wave_m * 64 + t * 16 + l15;
        aoff[t] = ar * 32 + ((q ^ swz(ar)) << 3);
        int br = wave_n * 64 + t * 16 + l15;
        boff[t] = br * 32 + ((q ^ swz(br)) << 3);
    }

    f32x4 acc[4][4] = {};

    for (int kt = 0; kt < KT; ++kt) {
        const u16* Asrc = (kt < 8) ? s0 : ((NSEG == 2 || kt < 16) ? s1 : s2);
        load_lds16(Asrc + a_goff + ((kt & 7) << 5), a_ldst);
        int k0 = kt << 5;
        load_lds16(bgp[0] + k0, bldst[0]);
        load_lds16(bgp[1] + k0, bldst[1]);
        __syncthreads();

        bf16x8 af[4], bfr[4];
        #pragma unroll
        for (int t = 0; t < 4; ++t) af[t]  = *(const bf16x8*)&Alds[aoff[t]];
        #pragma unroll
        for (int f = 0; f < 4; ++f) bfr[f] = *(const bf16x8*)&Blds[boff[f]];
        #pragma unroll
        for (int t = 0; t < 4; ++t)
            #pragma unroll
            for (int f = 0; f < 4; ++f)
                acc[t][f] = __builtin_amdgcn_mfma_f32_16x16x32_bf16(af[t], bfr[f], acc[t][f], 0, 0, 0);
        __syncthreads();
    }

    float bias[4], lsc[4], lbi[4];
    #pragma unroll
    for (int f = 0; f < 4; ++f) {
        int n = wave_n * 64 + f * 16 + l15;
        bias[f] = bcat[n]; lsc[f] = lns[n]; lbi[f] = lnb[n];
    }
    #pragma unroll
    for (int t = 0; t < 4; ++t)
        #pragma unroll
        for (int r = 0; r < 4; ++r) {
            float p = 0.f, pp = 0.f;
            #pragma unroll
            for (int f = 0; f < 4; ++f) {
                float v = acc[t][f][r] + bias[f];
                v = fmaxf(v, 0.f);
                acc[t][f][r] = v;
                p += v; pp += v * v;
            }
            #pragma unroll
            for (int off = 1; off < 16; off <<= 1) {
                p  += __shfl_xor(p,  off, 16);
                pp += __shfl_xor(pp, off, 16);
            }
            if (l15 == 0) {
                int row = wave_m * 64 + t * 16 + q * 4 + r;
                lnpart[row][wave_n][0] = p;
                lnpart[row][wave_n][1] = pp;
            }
        }
    __syncthreads();
    #pragma unroll
    for (int t = 0; t < 4; ++t)
        #pragma unroll
        for (int r = 0; r < 4; ++r) {
            int row = wave_m * 64 + t * 16 + q * 4 + r;
            int node = m0 + row;
            if (node < Nnodes) {
                float S1 = lnpart[row][0][0] + lnpart[row][1][0]
                         + lnpart[row][2][0] + lnpart[row][3][0];
                float S2 = lnpart[row][0][1] + lnpart[row][1][1]
                         + lnpart[row][2][1] + lnpart[row][3][1];
                float mean = S1 * (1.f / 256.f);
                float var  = fmaxf(S2 * (1.f / 256.f) - mean * mean, 0.f);
                float rstd = rsqrtf(var + LN_EPS);
                u16* op = Hout + (size_t)node * C;
                #pragma unroll
                for (int f = 0; f < 4; ++f) {
                    int n = wave_n * 64 + f * 16 + l15;
                    op[n] = f2bf((acc[t][f][r] - mean) * rstd * lsc[f] + lbi[f]);
                }
            }
        }
}

// ---- final GEMM (128x128 tile): h2(bf16, in d_out) @ Woutb^T + bout -> fp32 in place
__global__ __launch_bounds__(512, 4) void final_gemm(
    const u16* __restrict__ A, const u16* __restrict__ W,
    const float* __restrict__ bout, float* __restrict__ out, int Nnodes)
{
    __shared__ u16 Alds[128 * 32];   // 8 KB
    __shared__ u16 Blds[128 * 32];   // 8 KB

    const int tid = threadIdx.x;
    const int wave = tid >> 6, lane = tid & 63;
    const int wave_m = wave & 1, wave_n = wave >> 1;   // 2 x 4
    const int q = lane >> 4, l15 = lane & 15;
    const int m0 = blockIdx.x * 128;

    const int srow = (wave << 4) + (lane >> 2);
    int anode = m0 + srow; if (anode >= Nnodes) anode = Nnodes - 1;
    const int asc = (lane & 3) ^ swz(srow);
    const size_t a_goff = (size_t)anode * C + asc * 8;
    u16* a_ldst = Alds + (wave << 9);

    const int bsc = (lane & 3) ^ swz(srow);
    const u16* bgp = W + srow * C + bsc * 8;
    u16* bldst = Blds + (wave << 9);

    int aoff[4], boff[2];
    #pragma unroll
    for (int t = 0; t < 4; ++t) {
        int ar = wave_m * 64 + t * 16 + l15;
        aoff[t] = ar * 32 + ((q ^ swz(ar)) << 3);
    }
    #pragma unroll
    for (int f = 0; f < 2; ++f) {
        int br = wave_n * 32 + f * 16 + l15;
        boff[f] = br * 32 + ((q ^ swz(br)) << 3);
    }

    f32x4 acc[4][2] = {};

    for (int kt = 0; kt < 8; ++kt) {
        int k0 = kt << 5;
        load_lds16(A + a_goff + k0, a_ldst);
        load_lds16(bgp + k0, bldst);
        __syncthreads();

        bf16x8 af[4], bfr[2];
        #pragma unroll
        for (int t = 0; t < 4; ++t) af[t]  = *(const bf16x8*)&Alds[aoff[t]];
        #pragma unroll
        for (int f = 0; f < 2; ++f) bfr[f] = *(const bf16x8*)&Blds[boff[f]];
        #pragma unroll
        for (int t = 0; t < 4; ++t)
            #pragma unroll
            for (int f = 0; f < 2; ++f)
                acc[t][f] = __builtin_amdgcn_mfma_f32_16x16x32_bf16(af[t], bfr[f], acc[t][f], 0, 0, 0);
        __syncthreads();
    }

    float bias[2];
    #pragma unroll
    for (int f = 0; f < 2; ++f) bias[f] = bout[wave_n * 32 + f * 16 + l15];
    #pragma unroll
    for (int t = 0; t < 4; ++t)
        #pragma unroll
        for (int r = 0; r < 4; ++r) {
            int row = wave_m * 64 + t * 16 + q * 4 + r;
            int node = m0 + row;
            if (node < Nnodes) {
                float* op = out + (size_t)node * OUTC;
                #pragma unroll
                for (int f = 0; f < 2; ++f) {
                    int n = wave_n * 32 + f * 16 + l15;
                    op[n] = acc[t][f][r] + bias[f];
                }
            }
        }
}

extern "C" void kernel_launch(void* const* d_in, const int* in_sizes, int n_in,
                              void* d_out, int out_size, void* d_ws, size_t ws_size,
                              hipStream_t stream)
{
    const float* x    = (const float*)d_in[0];
    const int*   ei0  = (const int*)d_in[1];
    const int*   ei1  = (const int*)d_in[2];
    const float* wl0  = (const float*)d_in[3];
    const float* bl0  = (const float*)d_in[4];
    const float* w00  = (const float*)d_in[5];
    const float* b00  = (const float*)d_in[6];
    const float* w10  = (const float*)d_in[7];
    const float* b10  = (const float*)d_in[8];
    const float* gate0= (const float*)d_in[9];
    const float* lns0 = (const float*)d_in[10];
    const float* lnb0 = (const float*)d_in[11];
    const float* wl1  = (const float*)d_in[12];
    const float* bl1  = (const float*)d_in[13];
    const float* w01  = (const float*)d_in[14];
    const float* b01  = (const float*)d_in[15];
    const float* w11  = (const float*)d_in[16];
    const float* b11  = (const float*)d_in[17];
    const float* gate1= (const float*)d_in[18];
    const float* lns1 = (const float*)d_in[19];
    const float* lnb1 = (const float*)d_in[20];
    const float* Wout = (const float*)d_in[21];
    const float* bout = (const float*)d_in[22];

    const int N = in_sizes[0] / C;     // 100000
    const int E = in_sizes[1] / 2;     // 400000

    // workspace (~161 MiB)
    char* w = (char*)d_ws;
    u16*   WcatA = (u16*)w;   w += (size_t)256 * 512 * 2;
    u16*   WcatB = (u16*)w;   w += (size_t)256 * 768 * 2;
    u16*   Woutb = (u16*)w;   w += (size_t)OUTC * C * 2;
    float* bcat  = (float*)w; w += 4096;
    int*   cnt1  = (int*)w;   w += (size_t)N * 4;       // 4 contiguous, one memset
    int*   deg1  = (int*)w;   w += (size_t)N * 4;
    int*   cnt0  = (int*)w;   w += (size_t)N * 4;
    int*   deg0  = (int*)w;   w += (size_t)N * 4;
    int*   off1  = (int*)w;   w += (((size_t)(N + 1) * 4) + 255) & ~255ull;
    int*   off0  = (int*)w;   w += (((size_t)(N + 1) * 4) + 255) & ~255ull;
    int*   parts1= (int*)w;   w += 4096;
    int*   parts0= (int*)w;   w += 4096;
    int*   ed1   = (int*)w;   w += (size_t)E * 4;
    int*   ed0   = (int*)w;   w += (size_t)E * 4;
    u16*   xb    = (u16*)w;   w += (size_t)N * C * 2;   // 51.2 MB bf16 copy of x
    u16*   aggb  = (u16*)w;   w += (size_t)N * C * 2;   // 51.2 MB (reused both layers)
    u16*   h1    = (u16*)w;   w += (size_t)N * C * 2;   // 51.2 MB

    const int eb_grid = (E + 255) / 256;
    const int nblk    = (N + 255) / 256;                // 391 <= 1024
    const int gt_grid = (N + 3) / 4;
    const int gm_grid = (N + 127) / 128;
    const size_t n8   = (size_t)N * C / 8;
    const int xc_blk  = (int)((n8 + 255) / 256);
    u16* h2 = (u16*)d_out;   // layer-B bf16 output in d_out; final_gemm overwrites in place

    hipMemsetAsync(cnt1, 0, (size_t)4 * N * 4, stream);
    prep_combo<<<PREP_BLK + xc_blk, 256, 0, stream>>>(
        wl0, w00, w10, bl0, b00, b10, gate0,
        wl1, w01, w11, bl1, b01, b11, gate1,
        Wout, x, WcatA, WcatB, Woutb, bcat, xb, n8);

    // ---- CSR builds, both graphs per launch ----
    count_edges2 <<<2 * eb_grid, 256, 0, stream>>>(ei1, ei0, cnt1, deg1, cnt0, deg0, E, N, eb_grid);
    block_sums2  <<<2 * nblk, 256, 0, stream>>>(cnt1, cnt0, parts1, parts0, N, nblk);
    scan_partials2<<<2, 1024, 0, stream>>>(parts1, parts0, nblk);
    make_offsets2<<<2 * nblk, 256, 0, stream>>>(cnt1, cnt0, parts1, parts0, off1, off0, N, nblk);
    fill_edges2  <<<2 * eb_grid, 256, 0, stream>>>(ei1, ei0, cnt1, cnt0, ed1, ed0, E, N, eb_grid);

    // ---- layer A: graph ei1, params *1, h = x0 = xb; K = 512 (w0,w1 folded) ----
    gather_kernel<<<gt_grid, 256, 0, stream>>>(off1, ed1, deg1, xb, aggb, N);
    layer_gemm<2><<<gm_grid, 512, 0, stream>>>(aggb, xb, nullptr, WcatA, bcat,
                                               lns1, lnb1, h1, N);

    // ---- layer B: graph ei0, params *0, h = h1, x0 = xb; K = 768 ----
    gather_kernel<<<gt_grid, 256, 0, stream>>>(off0, ed0, deg0, h1, aggb, N);
    layer_gemm<3><<<gm_grid, 512, 0, stream>>>(aggb, h1, xb, WcatB, bcat + C,
                                               lns0, lnb0, h2, N);

    // ---- output projection (128x128 tile, in place over d_out) ----
    final_gemm<<<gm_grid, 512, 0, stream>>>(h2, Woutb, bout, (float*)d_out, N);
}